// Round 2
// baseline (8971.474 us; speedup 1.0000x reference)
//
#include <hip/hip_runtime.h>

// ---------------------------------------------------------------------------
// Seq2SeqAttentionDecoder — round 2
//  * big GEMMs (keys, gi0x, logits) -> bf16 MFMA (m97-style 128x128 tile,
//    global_load_lds width 16, mfma_f32_16x16x32_bf16)
//  * scores+softmax+ctx merged into one kernel (k_attn)
//  * recurrence math unchanged (fp32) -> h trajectory identical to round 1
//  * Wout_bf16 (65.5 MB) aliases loop-dead workspace (converted after loop)
// ---------------------------------------------------------------------------

#define BB 32
#define TT 64
#define SS 128
#define HH 1024
#define EE 512
#define VV 32000
#define H3 3072
#define NEGV (-1000000.0f)
#define KS 8

typedef __attribute__((ext_vector_type(8))) short s16x8;
typedef __attribute__((ext_vector_type(4))) float f32x4;

__device__ __forceinline__ unsigned short f2bf(float f) {
  unsigned int u = __builtin_bit_cast(unsigned int, f);
  unsigned int r = (u + 0x7FFFu + ((u >> 16) & 1u)) >> 16;   // RNE
  return (unsigned short)r;
}

// ---------- init h0/h1 ----------
__global__ __launch_bounds__(256) void k_init_h(const float* __restrict__ hid,
                                                float* __restrict__ h0,
                                                float* __restrict__ h1) {
  int i = blockIdx.x * 256 + threadIdx.x;
  if (i < BB * HH) h0[i] = hid[i];
  else             h1[i - BB * HH] = hid[i];
}

// ---------- gather xs[r=t*B+b][e] = bf16(emb[X[b][t]][e]) ----------
__global__ __launch_bounds__(256) void k_gather(const int* __restrict__ X,
                                                const float* __restrict__ emb,
                                                unsigned short* __restrict__ xs) {
  int idx = blockIdx.x * 256 + threadIdx.x;    // T*B*E/4 quads
  int r = idx >> 7, c4 = (idx & 127) << 2;
  int td = r >> 5, b = r & 31;
  int tok = X[b * TT + td];
  float4 v = *(const float4*)(emb + (size_t)tok * EE + c4);
  ushort4 o;
  o.x = f2bf(v.x); o.y = f2bf(v.y); o.z = f2bf(v.z); o.w = f2bf(v.w);
  *(ushort4*)(xs + (size_t)r * EE + c4) = o;
}

// ---------- strided fp32 -> packed bf16 convert (cols must be pow2*4) ----
__global__ __launch_bounds__(256) void k_conv(const float* __restrict__ src,
                                              unsigned short* __restrict__ dst,
                                              int rows, int cshift /*log2(cols/4)*/,
                                              int ld) {
  size_t total4 = (size_t)rows << cshift;
  int cols4 = 1 << cshift;
  for (size_t i = (size_t)blockIdx.x * 256 + threadIdx.x; i < total4;
       i += (size_t)gridDim.x * 256) {
    size_t r = i >> cshift;
    int c4 = (int)(i & (cols4 - 1)) << 2;
    float4 v = *(const float4*)(src + r * ld + c4);
    ushort4 o;
    o.x = f2bf(v.x); o.y = f2bf(v.y); o.z = f2bf(v.z); o.w = f2bf(v.w);
    *(ushort4*)(dst + (r << (cshift + 2)) + c4) = o;
  }
}

// ---------- bf16 MFMA GEMM: C[M,N] = A[M,K] @ W[N,K]^T (+bias) ----------
// 128x128 tile, BK=32, 256 threads (4 waves, 2x2), 64x64 per wave (4x4 frags).
// A,W packed bf16 row-major K-contiguous. C fp32. M,N,K multiples of 128/128/32.
__global__ __launch_bounds__(256) void k_gemm_bf16(
    const unsigned short* __restrict__ A, const unsigned short* __restrict__ W,
    const float* __restrict__ bias, float* __restrict__ C,
    int M, int N, int K, int permuteBT) {
  __shared__ unsigned short As[128 * 32];   // [row][k] row-major, 8 KB
  __shared__ unsigned short Bs[128 * 32];
  const int m0 = blockIdx.y * 128, n0 = blockIdx.x * 128;
  const int t = threadIdx.x;
  const int lane = t & 63, w = t >> 6;
  const int wr = w >> 1, wc = w & 1;        // wave 2x2 grid, 64x64 each
  const int fr = lane & 15, fq = lane >> 4; // fragment row / k-quad
  const int srow = t >> 2;                  // staging row 0..63 (+64 2nd issue)
  const int scol = (t & 3) * 8;             // staging k elem offset
  f32x4 acc[4][4] = {};
  for (int k0 = 0; k0 < K; k0 += 32) {
#pragma unroll
    for (int i = 0; i < 2; ++i) {
      // LDS dest: wave-uniform base + lane*16B (linear); global src per-lane
      __builtin_amdgcn_global_load_lds(
          (const __attribute__((address_space(1))) void*)(A + (size_t)(m0 + i * 64 + srow) * K + k0 + scol),
          (__attribute__((address_space(3))) void*)((char*)As + i * 4096 + w * 1024),
          16, 0, 0);
      __builtin_amdgcn_global_load_lds(
          (const __attribute__((address_space(1))) void*)(W + (size_t)(n0 + i * 64 + srow) * K + k0 + scol),
          (__attribute__((address_space(3))) void*)((char*)Bs + i * 4096 + w * 1024),
          16, 0, 0);
    }
    __syncthreads();                         // drains vmcnt -> LDS valid
    s16x8 af[4], bf[4];
#pragma unroll
    for (int mi = 0; mi < 4; ++mi)
      af[mi] = *(const s16x8*)(As + (wr * 64 + mi * 16 + fr) * 32 + fq * 8);
#pragma unroll
    for (int ni = 0; ni < 4; ++ni)
      bf[ni] = *(const s16x8*)(Bs + (wc * 64 + ni * 16 + fr) * 32 + fq * 8);
#pragma unroll
    for (int mi = 0; mi < 4; ++mi)
#pragma unroll
      for (int ni = 0; ni < 4; ++ni)
        acc[mi][ni] = __builtin_amdgcn_mfma_f32_16x16x32_bf16(
            af[mi], bf[ni], acc[mi][ni], 0, 0, 0);
    __syncthreads();
  }
  // epilogue: D col = lane&15, row = (lane>>4)*4 + j  (m89-verified)
#pragma unroll
  for (int mi = 0; mi < 4; ++mi) {
#pragma unroll
    for (int ni = 0; ni < 4; ++ni) {
      int gc = n0 + wc * 64 + ni * 16 + fr;
      float bv = bias ? bias[gc] : 0.f;
#pragma unroll
      for (int j = 0; j < 4; ++j) {
        int gm = m0 + wr * 64 + mi * 16 + fq * 4 + j;
        size_t ro = permuteBT ? ((size_t)((gm & 31) * TT + (gm >> 5))) * N
                              : (size_t)gm * N;
        C[ro + gc] = acc[mi][ni][j] + bv;
      }
    }
  }
}

// ---------- recurrent skinny split-K GEMM (fp32, unchanged) ----------
__global__ __launch_bounds__(128) void k_gemm_rec(
    const float* __restrict__ A0, const float* __restrict__ W0, int ldw0,
    float* __restrict__ C0,
    const float* __restrict__ A1, const float* __restrict__ W1, int ldw1,
    float* __restrict__ C1, int N) {
  __shared__ float As[64][36];
  __shared__ float Ws[64][68];
  const int set = blockIdx.z;
  const float* A = set ? A1 : A0;
  const float* W = set ? W1 : W0;
  const int ldw  = set ? ldw1 : ldw0;
  float* C       = set ? C1 : C0;
  const int n0 = blockIdx.x * 64;
  const int kbeg = blockIdx.y * (HH / KS);
  const int t = threadIdx.x;
  const int tn = t & 15, tmg = t >> 4;
  float acc[4][4] = {};
  for (int k0 = kbeg; k0 < kbeg + HH / KS; k0 += 64) {
#pragma unroll
    for (int qq = 0; qq < 4; ++qq) {
      int f = t + 128 * qq;
      int row = f >> 4, c4 = (f & 15) << 2;
      float4 v = *(const float4*)(A + (size_t)row * HH + k0 + c4);
      As[c4 + 0][row] = v.x; As[c4 + 1][row] = v.y;
      As[c4 + 2][row] = v.z; As[c4 + 3][row] = v.w;
    }
#pragma unroll
    for (int qq = 0; qq < 8; ++qq) {
      int f = t + 128 * qq;
      int row = f >> 4, c4 = (f & 15) << 2;
      float4 v = *(const float4*)(W + (size_t)(n0 + row) * ldw + k0 + c4);
      Ws[c4 + 0][row] = v.x; Ws[c4 + 1][row] = v.y;
      Ws[c4 + 2][row] = v.z; Ws[c4 + 3][row] = v.w;
    }
    __syncthreads();
#pragma unroll
    for (int k = 0; k < 64; ++k) {
      float4 a = *(const float4*)&As[k][tmg << 2];
      float4 w = *(const float4*)&Ws[k][tn << 2];
      acc[0][0] = fmaf(a.x, w.x, acc[0][0]); acc[0][1] = fmaf(a.x, w.y, acc[0][1]);
      acc[0][2] = fmaf(a.x, w.z, acc[0][2]); acc[0][3] = fmaf(a.x, w.w, acc[0][3]);
      acc[1][0] = fmaf(a.y, w.x, acc[1][0]); acc[1][1] = fmaf(a.y, w.y, acc[1][1]);
      acc[1][2] = fmaf(a.y, w.z, acc[1][2]); acc[1][3] = fmaf(a.y, w.w, acc[1][3]);
      acc[2][0] = fmaf(a.z, w.x, acc[2][0]); acc[2][1] = fmaf(a.z, w.y, acc[2][1]);
      acc[2][2] = fmaf(a.z, w.z, acc[2][2]); acc[2][3] = fmaf(a.z, w.w, acc[2][3]);
      acc[3][0] = fmaf(a.w, w.x, acc[3][0]); acc[3][1] = fmaf(a.w, w.y, acc[3][1]);
      acc[3][2] = fmaf(a.w, w.z, acc[3][2]); acc[3][3] = fmaf(a.w, w.w, acc[3][3]);
    }
    __syncthreads();
  }
#pragma unroll
  for (int i = 0; i < 4; ++i) {
    int m = tmg * 4 + i;
    float4 v; v.x = acc[i][0]; v.y = acc[i][1]; v.z = acc[i][2]; v.w = acc[i][3];
    *(float4*)(C + ((size_t)blockIdx.y * BB + m) * N + n0 + tn * 4) = v;
  }
}

// ---------- attention: q-reduce + scores + softmax + ctx, one block per b ----
__global__ __launch_bounds__(1024) void k_attn(
    const float* __restrict__ qpart, const float* __restrict__ keys,
    const float* __restrict__ wv, const int* __restrict__ vlen,
    const float* __restrict__ enc, float* __restrict__ ctx) {
  __shared__ float qs[HH];
  __shared__ float sc[SS];
  const int b = blockIdx.x, t = threadIdx.x;
  // reduce q partials (one h per thread)
  {
    float s = 0;
#pragma unroll
    for (int p = 0; p < KS; ++p)
      s += qpart[(size_t)p * BB * HH + (size_t)b * HH + t];
    qs[t] = s;
  }
  __syncthreads();
  // scores: 8 threads per s
  const int si = t >> 3, g = t & 7;
  {
    const float* kb = keys + ((size_t)b * SS + si) * HH;
    float a = 0;
    for (int h = g; h < HH; h += 8) a = fmaf(tanhf(qs[h] + kb[h]), wv[h], a);
    a += __shfl_xor(a, 1); a += __shfl_xor(a, 2); a += __shfl_xor(a, 4);
    if (g == 0) sc[si] = (si < vlen[b]) ? a : NEGV;
  }
  __syncthreads();
  // softmax (redundant serial over 128 — LDS broadcast, cheap)
  float mx = sc[0];
#pragma unroll 8
  for (int s = 1; s < SS; ++s) mx = fmaxf(mx, sc[s]);
  float e = (t < SS) ? expf(sc[t] - mx) : 0.f;
  __syncthreads();
  if (t < SS) sc[t] = e;
  __syncthreads();
  float sum = 0;
#pragma unroll 8
  for (int s = 0; s < SS; ++s) sum += sc[s];
  const float inv = 1.f / sum;
  // ctx: one h per thread
  float a = 0;
  const float* ep = enc + (size_t)b * SS * HH + t;
#pragma unroll 4
  for (int s = 0; s < SS; ++s) a = fmaf(sc[s], ep[(size_t)s * HH], a);
  ctx[b * HH + t] = a * inv;
}

// ---------- GRU elementwise (reduces split-K partials) ----------
__global__ __launch_bounds__(256) void k_gru(
    const float* __restrict__ gix, const float* __restrict__ giP,
    const float* __restrict__ ghP, const float* __restrict__ bih,
    const float* __restrict__ bhh, float* __restrict__ h,
    unsigned short* __restrict__ outrow) {
  const int idx = blockIdx.x * 256 + threadIdx.x;
  const int b = idx >> 10, hh = idx & 1023;
  const size_t base3 = (size_t)b * H3;
  float ir = 0, iz = 0, inn = 0, hr = 0, hz = 0, hn = 0;
#pragma unroll
  for (int p = 0; p < KS; ++p) {
    const size_t pb = (size_t)p * BB * H3 + base3 + hh;
    ir += giP[pb]; iz += giP[pb + HH]; inn += giP[pb + 2 * HH];
    hr += ghP[pb]; hz += ghP[pb + HH]; hn += ghP[pb + 2 * HH];
  }
  if (gix) { ir += gix[base3 + hh]; iz += gix[base3 + HH + hh];
             inn += gix[base3 + 2 * HH + hh]; }
  if (bih) { ir += bih[hh]; iz += bih[HH + hh]; inn += bih[2 * HH + hh]; }
  hr += bhh[hh]; hz += bhh[HH + hh]; hn += bhh[2 * HH + hh];
  float r = 1.f / (1.f + expf(-(ir + hr)));
  float z = 1.f / (1.f + expf(-(iz + hz)));
  float n = tanhf(inn + r * hn);
  float hv = (1.f - z) * n + z * h[idx];
  h[idx] = hv;
  if (outrow) outrow[idx] = f2bf(hv);
}

// ---------------------------------------------------------------------------
extern "C" void kernel_launch(void* const* d_in, const int* in_sizes, int n_in,
                              void* d_out, int out_size, void* d_ws,
                              size_t ws_size, hipStream_t stream) {
  const int*   X    = (const int*)  d_in[0];
  const float* enc  = (const float*)d_in[1];
  const float* hid  = (const float*)d_in[2];
  const int*   vlen = (const int*)  d_in[3];
  const float* emb  = (const float*)d_in[4];
  const float* Wq   = (const float*)d_in[5];
  const float* Wk   = (const float*)d_in[6];
  const float* wv   = (const float*)d_in[7];
  const float* Wih0 = (const float*)d_in[8];
  const float* Whh0 = (const float*)d_in[9];
  const float* bih0 = (const float*)d_in[10];
  const float* bhh0 = (const float*)d_in[11];
  const float* Wih1 = (const float*)d_in[12];
  const float* Whh1 = (const float*)d_in[13];
  const float* bih1 = (const float*)d_in[14];
  const float* bhh1 = (const float*)d_in[15];
  const float* Wout = (const float*)d_in[16];
  const float* bout = (const float*)d_in[17];
  float* out = (float*)d_out;

  // ---- workspace layout (floats). Overlay region is dead after the loop and
  // gets reused for Wout_bf16 (16.384M floats = 65.5 MB < 71.3 MB overlay). ----
  float* ws = (float*)d_ws;
  float* keys   = ws;                              //  4,194,304 f
  float* gi0x   = keys  + (size_t)4194304;         //  6,291,456 f
  float* qpart  = gi0x  + (size_t)6291456;         //    262,144 f
  float* gicP   = qpart + (size_t)262144;          //    786,432 f
  float* ghP0   = gicP  + (size_t)786432;
  float* giP1   = ghP0  + (size_t)786432;
  float* ghP1   = giP1  + (size_t)786432;
  unsigned short* encb  = (unsigned short*)(ghP1 + (size_t)786432); // 4,194,304 u16
  unsigned short* wkb   = encb  + (size_t)4194304;  // 1,048,576 u16
  unsigned short* wih0b = wkb   + (size_t)1048576;  // 1,572,864 u16
  unsigned short* xsb   = wih0b + (size_t)1572864;  // 1,048,576 u16
  unsigned short* woutb = (unsigned short*)ws;      // ALIAS overlay (post-loop)
  float* pers   = ws + (size_t)17825792;            // 71.3 MB mark
  unsigned short* outsb = (unsigned short*)pers;    // 2,097,152 u16
  float* h0     = pers + (size_t)1048576;
  float* h1     = h0 + 32768;
  float* ctx    = h1 + 32768;                       // end ~75.9 MB

  k_init_h<<<256, 256, 0, stream>>>(hid, h0, h1);
  k_gather<<<1024, 256, 0, stream>>>(X, emb, xsb);
  k_conv<<<512, 256, 0, stream>>>(enc, encb, BB * SS, 8, HH);
  k_conv<<<256, 256, 0, stream>>>(Wk, wkb, HH, 8, HH);
  k_conv<<<256, 256, 0, stream>>>(Wih0 + HH, wih0b, H3, 7, HH + EE);
  // keys = enc @ Wk^T
  k_gemm_bf16<<<dim3(8, 32), 256, 0, stream>>>(encb, wkb, nullptr, keys,
                                               BB * SS, HH, HH, 0);
  // gi0x = xs @ W_ih0[:,H:]^T + b_ih0
  k_gemm_bf16<<<dim3(24, 16), 256, 0, stream>>>(xsb, wih0b, bih0, gi0x,
                                                TT * BB, H3, EE, 0);

  for (int td = 0; td < TT; ++td) {
    k_gemm_rec<<<dim3(16, KS, 1), 128, 0, stream>>>(h1, Wq, HH, qpart,
                                                    h1, Wq, HH, qpart, HH);
    k_attn<<<32, 1024, 0, stream>>>(qpart, keys, wv, vlen, enc, ctx);
    k_gemm_rec<<<dim3(48, KS, 2), 128, 0, stream>>>(ctx, Wih0, HH + EE, gicP,
                                                    h0, Whh0, HH, ghP0, H3);
    k_gru<<<128, 256, 0, stream>>>(gi0x + (size_t)td * BB * H3, gicP, ghP0,
                                   nullptr, bhh0, h0, nullptr);
    k_gemm_rec<<<dim3(48, KS, 2), 128, 0, stream>>>(h0, Wih1, HH, giP1,
                                                    h1, Whh1, HH, ghP1, H3);
    k_gru<<<128, 256, 0, stream>>>(nullptr, giP1, ghP1, bih1, bhh1, h1,
                                   outsb + (size_t)td * BB * HH);
  }
  // Wout -> bf16 into overlay (keys/gi0x/partials dead now), then logits GEMM
  k_conv<<<2048, 256, 0, stream>>>(Wout, woutb, VV, 8, HH);
  k_gemm_bf16<<<dim3(250, 16), 256, 0, stream>>>(outsb, woutb, bout, out,
                                                 TT * BB, VV, HH, 1);
}